// Round 11
// baseline (489.880 us; speedup 1.0000x reference)
//
#include <hip/hip_runtime.h>
#include <hip/hip_bf16.h>

// GCN (3-layer, JK=sum) on MI355X.
// R15b: identical resubmit of R15 (container failed twice — infra; kernel
//      never ran. Audit: no OOB, unroll arrays statically indexed, numerics
//      = R14 + ~1e-6 reassociation).
// R15: spmm gather loop: (a) hsb stored as BIASED uint8 (q+128) so decode is
//      v_cvt_f32_ubyteN + fmac (2 VALU/ch vs 3 with signed bfe); per-row
//      correction -128*sum(sc) applied once (reassociation err ~1e-6).
//      (b) 16-edge-deep unroll (was 8): 2x outstanding L3 gathers — hsb is
//      L3-resident now (R14 FETCH 227->147MB), so exposed L3 latency is the
//      cost, not HBM bytes. VALUBusy was 36%.
// R14: coalesced two-phase bnred; k_bktscan folded into part2/csr2.
// R13: hsb int8 + per-row scale (128B gather granule). R11: JK-sum deferred
//      to final spmm. R10: h bf16. R9: BN affine fused into gemm A-path.
// R8: LDS radix partition CSR build. R7: MFMA gemm.

constexpr int NN = 100000;
constexpr int EE = 1600000;
constexpr int DD = 128;
constexpr float BN_EPS = 1e-5f;
constexpr int NPAD = 100096;
constexpr int SPMM_GRID = NN / 16;              // 6250
constexpr int GEMM_GRID = (NN + 63) / 64;       // 1563
constexpr int BNRED_GRID = 250;                 // 6250/25 rows each

// radix partition params
constexpr int NBK = (NN + 511) / 512;           // 196 coarse buckets (dst>>9)
constexpr int PB = 4096;                        // edges per partition block
constexpr int PART_GRID = (EE + PB - 1) / PB;   // 391
constexpr int CSTRIDE = 400;                    // >= PART_GRID, count-table stride
constexpr int CAPL = 10240;                     // LDS colseg capacity

typedef __attribute__((ext_vector_type(8))) short bf16x8;
typedef __attribute__((ext_vector_type(4))) float f32x4;

__device__ __forceinline__ float bfhi(unsigned int u) {
  union { unsigned int i; float f; } v; v.i = u & 0xffff0000u; return v.f;
}
__device__ __forceinline__ float bflo(unsigned int u) {
  union { unsigned int i; float f; } v; v.i = u << 16; return v.f;
}
__device__ __forceinline__ unsigned short f2bf(float f) {
  union { float f; unsigned int i; } v;
  v.f = f;
  unsigned int r = v.i + 0x7FFFu + ((v.i >> 16) & 1u);   // RNE
  return (unsigned short)(r >> 16);
}
__device__ __forceinline__ unsigned pack2(float lo, float hi) {
  return (unsigned)f2bf(lo) | ((unsigned)f2bf(hi) << 16);
}
// biased-uint8 decode: 8 channels from one uint2 (v_cvt_f32_ubyteN pattern)
__device__ __forceinline__ void accu8(uint2 u, float sc, float4& a0, float4& a1) {
  a0.x = fmaf(sc, (float)(u.x & 0xffu), a0.x);
  a0.y = fmaf(sc, (float)((u.x >> 8) & 0xffu), a0.y);
  a0.z = fmaf(sc, (float)((u.x >> 16) & 0xffu), a0.z);
  a0.w = fmaf(sc, (float)(u.x >> 24), a0.w);
  a1.x = fmaf(sc, (float)(u.y & 0xffu), a1.x);
  a1.y = fmaf(sc, (float)((u.y >> 8) & 0xffu), a1.y);
  a1.z = fmaf(sc, (float)((u.y >> 16) & 0xffu), a1.z);
  a1.w = fmaf(sc, (float)(u.y >> 24), a1.w);
}
__device__ __forceinline__ int wave_incl_scan(int v, int lane) {
#pragma unroll
  for (int off = 1; off < 64; off <<= 1) {
    int x = __shfl_up(v, off, 64);
    if (lane >= off) v += x;
  }
  return v;
}

// --- CSR build pass 1: per-(block,bucket) counts, transposed [bkt][blk] ---
__global__ __launch_bounds__(256)
void k_cnt(const int* __restrict__ dst, int* __restrict__ cntT) {
  __shared__ int cnt[256];
  const int t = threadIdx.x;
  const int e0 = blockIdx.x * PB;
  const int nv = min(PB, EE - e0);
  cnt[t] = 0;
  __syncthreads();
  for (int i = t; i < nv; i += 256)
    atomicAdd(&cnt[dst[e0 + i] >> 9], 1);
  __syncthreads();
  if (t < NBK) cntT[t * CSTRIDE + blockIdx.x] = cnt[t];
}

// --- per-bucket column scan over blocks; gtot[bkt] = total edges of bkt ---
__global__ __launch_bounds__(64)
void k_colscan(const int* __restrict__ cntT, int* __restrict__ baseT,
               int* __restrict__ gtot) {
  const int b = blockIdx.x;
  const int lane = threadIdx.x;
  int c[7];
  int ls = 0;
#pragma unroll
  for (int j = 0; j < 7; ++j) {
    const int idx = lane * 7 + j;
    c[j] = (idx < PART_GRID) ? cntT[b * CSTRIDE + idx] : 0;
    ls += c[j];
  }
  const int is = wave_incl_scan(ls, lane);
  int run = is - ls;
#pragma unroll
  for (int j = 0; j < 7; ++j) {
    const int idx = lane * 7 + j;
    if (idx < PART_GRID) baseT[b * CSTRIDE + idx] = run;
    run += c[j];
  }
  if (lane == 63) gtot[b] = is;
}

// --- CSR build pass 2: LDS counting sort per block, coalesced ebuf writes ---
__global__ __launch_bounds__(256)
void k_part2(const int* __restrict__ src, const int* __restrict__ dst,
             const int* __restrict__ baseT, const int* __restrict__ gtot,
             unsigned* __restrict__ ebuf) {
  __shared__ unsigned sorted[PB];
  __shared__ unsigned char sortedb[PB];
  alignas(16) __shared__ int cnt[256];
  __shared__ int cur[256], start[256], gbase[256];
  __shared__ int bktb[200];
  const int t = threadIdx.x;
  const int lane = t & 63;
  const int e0 = blockIdx.x * PB;
  const int nv = min(PB, EE - e0);
  cnt[t] = 0;
  if (t < 64) {   // recompute exclusive bucket-base scan from gtot
    int c[4];
    int ls = 0;
#pragma unroll
    for (int j = 0; j < 4; ++j) {
      const int idx = t * 4 + j;
      c[j] = (idx < NBK) ? gtot[idx] : 0;
      ls += c[j];
    }
    const int is = wave_incl_scan(ls, t);
    int run = is - ls;
#pragma unroll
    for (int j = 0; j < 4; ++j) {
      const int idx = t * 4 + j;
      if (idx < NBK) bktb[idx] = run;
      run += c[j];
    }
  }
  __syncthreads();
  if (t < NBK) gbase[t] = bktb[t] + baseT[t * CSTRIDE + blockIdx.x];
  int es[PB / 256], ed[PB / 256];
#pragma unroll
  for (int j = 0; j < PB / 256; ++j) {
    const int i = t + j * 256;
    if (i < nv) {
      es[j] = src[e0 + i];
      ed[j] = dst[e0 + i];
      atomicAdd(&cnt[ed[j] >> 9], 1);
    } else {
      ed[j] = -1;
    }
  }
  __syncthreads();
  if (t < 64) {
    const int4 c = *(const int4*)&cnt[lane * 4];
    const int ls = c.x + c.y + c.z + c.w;
    const int is = wave_incl_scan(ls, lane);
    int run = is - ls;
    start[lane * 4] = run; cur[lane * 4] = run; run += c.x;
    start[lane * 4 + 1] = run; cur[lane * 4 + 1] = run; run += c.y;
    start[lane * 4 + 2] = run; cur[lane * 4 + 2] = run; run += c.z;
    start[lane * 4 + 3] = run; cur[lane * 4 + 3] = run;
  }
  __syncthreads();
#pragma unroll
  for (int j = 0; j < PB / 256; ++j) {
    if (ed[j] >= 0) {
      const int bkt = ed[j] >> 9;
      const int p = atomicAdd(&cur[bkt], 1);
      sorted[p] = ((unsigned)es[j] << 9) | (unsigned)(ed[j] & 511);
      sortedb[p] = (unsigned char)bkt;
    }
  }
  __syncthreads();
  for (int i = t; i < nv; i += 256) {
    const int bkt = sortedb[i];
    ebuf[(size_t)gbase[bkt] + (i - start[bkt])] = sorted[i];
  }
}

// --- CSR finish: one block per bucket, all writes coalesced ---
__global__ __launch_bounds__(256)
void k_csr2(const unsigned* __restrict__ ebuf, const int* __restrict__ gtot,
            int* __restrict__ rowptr, int* __restrict__ col,
            float* __restrict__ dinv) {
  __shared__ int rowcnt[512], rowbase[512], rowcur[512];
  __shared__ int bktb[200];
  __shared__ unsigned colseg[CAPL];
  const int b = blockIdx.x;
  const int t = threadIdx.x;
  if (t < 64) {   // recompute exclusive bucket-base scan (+ total at [NBK])
    int c[4];
    int ls = 0;
#pragma unroll
    for (int j = 0; j < 4; ++j) {
      const int idx = t * 4 + j;
      c[j] = (idx < NBK) ? gtot[idx] : 0;
      ls += c[j];
    }
    const int is = wave_incl_scan(ls, t);
    int run = is - ls;
#pragma unroll
    for (int j = 0; j < 4; ++j) {
      const int idx = t * 4 + j;
      if (idx < NBK) bktb[idx] = run;
      run += c[j];
    }
    if (t == 63) bktb[NBK] = is;
  }
  rowcnt[t] = 0;
  rowcnt[t + 256] = 0;
  __syncthreads();
  const int ebase = bktb[b];
  const int n = min(bktb[b + 1] - ebase, CAPL);
  const unsigned* eb = &ebuf[ebase];
  for (int i = t; i < n; i += 256)
    atomicAdd(&rowcnt[eb[i] & 511u], 1);
  __syncthreads();
  if (t < 64) {
    int v[8];
    int ls = 0;
#pragma unroll
    for (int j = 0; j < 8; ++j) { v[j] = rowcnt[t * 8 + j]; ls += v[j]; }
    const int is = wave_incl_scan(ls, t);
    int run = is - ls;
#pragma unroll
    for (int j = 0; j < 8; ++j) {
      rowbase[t * 8 + j] = run;
      rowcur[t * 8 + j] = run;
      run += v[j];
    }
  }
  __syncthreads();
#pragma unroll
  for (int h = 0; h < 2; ++h) {
    const int rl = t + h * 256;
    const int r = b * 512 + rl;
    if (r < NN) {
      rowptr[r] = ebase + rowbase[rl];
      dinv[r] = rsqrtf((float)rowcnt[rl] + 1.0f);
    }
  }
  if (b == NBK - 1 && t == 0) rowptr[NN] = ebase + n;
  for (int i = t; i < n; i += 256) {
    const unsigned u = eb[i];
    const int p = atomicAdd(&rowcur[u & 511u], 1);
    colseg[p] = u >> 9;
  }
  __syncthreads();
  for (int i = t; i < n; i += 256) col[ebase + i] = (int)colseg[i];
}

// --- W transpose+cvt: Wt[l][c][k] = bf16(W[l][k][c]) --- grid = 3 blocks
__global__ __launch_bounds__(256)
void k_wt(const float* __restrict__ W, unsigned short* __restrict__ Wt) {
  const float* Ws = W + (size_t)blockIdx.x * DD * DD;
  unsigned short* Wo = Wt + (size_t)blockIdx.x * DD * DD;
  for (int i = threadIdx.x; i < DD * DD; i += 256) {
    const int k = i >> 7, c = i & 127;
    Wo[c * DD + k] = f2bf(Ws[i]);
  }
}

// --- MFMA GEMM with optional fused BN affine on A; biased-uint8 output ---
__global__ __launch_bounds__(256)
void k_gemm(const float* __restrict__ hf, const unsigned short* __restrict__ hb,
            const unsigned short* __restrict__ Wt,
            const float* __restrict__ dinv, unsigned char* __restrict__ hs8,
            float* __restrict__ scalev, const float* __restrict__ ss) {
  const int lane = threadIdx.x & 63;
  const int wave = threadIdx.x >> 6;          // 0..3
  const int n15 = lane & 15;
  const int quad = lane >> 4;                 // 0..3
  const int rbase = blockIdx.x * 64 + wave * 16;
  const int r0 = rbase + n15;
  const int arow = (r0 < NN) ? r0 : NN - 1;   // clamped load row

  f32x4 acc[8];
#pragma unroll
  for (int ct = 0; ct < 8; ++ct) acc[ct] = (f32x4){0.f, 0.f, 0.f, 0.f};

#pragma unroll
  for (int kc = 0; kc < 4; ++kc) {
    const int k0 = kc * 32 + quad * 8;
    float4 a0, a1;
    if (hb) {   // bf16 h (one 16B load covers all 8 elems)
      const uint4 u = *(const uint4*)&hb[(size_t)arow * DD + k0];
      a0.x = bflo(u.x); a0.y = bfhi(u.x);
      a0.z = bflo(u.y); a0.w = bfhi(u.y);
      a1.x = bflo(u.z); a1.y = bfhi(u.z);
      a1.z = bflo(u.w); a1.w = bfhi(u.w);
    } else {
      a0 = *(const float4*)&hf[(size_t)arow * DD + k0];
      a1 = *(const float4*)&hf[(size_t)arow * DD + k0 + 4];
    }
    if (ss) {  // fused BatchNorm affine
      const float4 sc0 = *(const float4*)&ss[k0];
      const float4 sc1 = *(const float4*)&ss[k0 + 4];
      const float4 sh0 = *(const float4*)&ss[128 + k0];
      const float4 sh1 = *(const float4*)&ss[128 + k0 + 4];
      a0.x = fmaf(a0.x, sc0.x, sh0.x); a0.y = fmaf(a0.y, sc0.y, sh0.y);
      a0.z = fmaf(a0.z, sc0.z, sh0.z); a0.w = fmaf(a0.w, sc0.w, sh0.w);
      a1.x = fmaf(a1.x, sc1.x, sh1.x); a1.y = fmaf(a1.y, sc1.y, sh1.y);
      a1.z = fmaf(a1.z, sc1.z, sh1.z); a1.w = fmaf(a1.w, sc1.w, sh1.w);
    }
    bf16x8 af;
    af[0] = (short)f2bf(a0.x); af[1] = (short)f2bf(a0.y);
    af[2] = (short)f2bf(a0.z); af[3] = (short)f2bf(a0.w);
    af[4] = (short)f2bf(a1.x); af[5] = (short)f2bf(a1.y);
    af[6] = (short)f2bf(a1.z); af[7] = (short)f2bf(a1.w);
#pragma unroll
    for (int ct = 0; ct < 8; ++ct) {
      const bf16x8 bf = *(const bf16x8*)&Wt[(size_t)(ct * 16 + n15) * DD + k0];
      acc[ct] = __builtin_amdgcn_mfma_f32_16x16x32_bf16(af, bf, acc[ct], 0, 0, 0);
    }
  }

#pragma unroll
  for (int i = 0; i < 4; ++i) {
    const int r = rbase + quad * 4 + i;
    const int rr = (r < NN) ? r : NN - 1;
    const float dv = dinv[rr];
    float v[8];
    float m = 0.f;
#pragma unroll
    for (int ct = 0; ct < 8; ++ct) {
      v[ct] = acc[ct][i] * dv;
      m = fmaxf(m, fabsf(v[ct]));
    }
    // row max across the 16-lane column group (all lanes execute)
#pragma unroll
    for (int off = 1; off < 16; off <<= 1)
      m = fmaxf(m, __shfl_xor(m, off, 64));
    const float inv = (m > 0.f) ? 127.0f / m : 0.f;
    if (r < NN) {
#pragma unroll
      for (int ct = 0; ct < 8; ++ct) {
        const int q = __float2int_rn(v[ct] * inv) + 128;   // biased uint8
        hs8[(size_t)r * DD + ct * 16 + n15] = (unsigned char)(q & 0xff);
      }
      if (n15 == 0) scalev[r] = m * (1.0f / 127.0f);
    }
  }
}

// --- SpMM over biased-uint8 hsb + row scales: 16-edge-deep gather pipeline.
//     channel value = sum(sc*u) - 128*sum(sc). Dual accumulator pairs.
//     mode 0: hout = bf16(relu(...)), partials for BN stats.
//     mode 1: out = ((x + BN1(h1)) + BN2(h2)) + relu(...)  (full JK sum) ---
__global__ __launch_bounds__(256)
void k_spmm(const unsigned char* __restrict__ hs8,
            const float* __restrict__ scalev, const int* __restrict__ rowptr,
            const int* __restrict__ col, const float* __restrict__ dinv,
            const float* __restrict__ bias, unsigned short* __restrict__ hout,
            float* __restrict__ partials, const float* __restrict__ x,
            const unsigned short* __restrict__ h1b,
            const unsigned short* __restrict__ h2b,
            const float* __restrict__ ss, float* __restrict__ out,
            const int mode) {
  const int lane = threadIdx.x & 15;     // 16 lanes / row
  const int g = threadIdx.x >> 4;        // 0..15 rows / block
  const int c8 = lane * 8;               // channel (and byte) offset
  const int d = blockIdx.x * 16 + g;
  float4 a0 = make_float4(0.f, 0.f, 0.f, 0.f);
  float4 a1 = make_float4(0.f, 0.f, 0.f, 0.f);
  float4 c0 = a0, c1 = a0;               // second accumulator pair
  float ssA = 0.f, ssB = 0.f;            // scale sums (bias correction)
  float4 bs0 = a0, bs1 = a0, q0 = a0, q1 = a0;
  if (d < NN) {
    {
      const float sc = scalev[d];        // self-loop
      accu8(*(const uint2*)&hs8[(size_t)d * DD + c8], sc, a0, a1);
      ssA += sc;
    }
    int j = rowptr[d];
    const int e1 = rowptr[d + 1];
    for (; j + 15 < e1; j += 16) {       // 16 gathers in flight
      int s[16];
#pragma unroll
      for (int k = 0; k < 16; ++k) s[k] = col[j + k];
      uint2 u[16];
#pragma unroll
      for (int k = 0; k < 16; ++k)
        u[k] = *(const uint2*)&hs8[(size_t)s[k] * DD + c8];
      float f[16];
#pragma unroll
      for (int k = 0; k < 16; ++k) f[k] = scalev[s[k]];
#pragma unroll
      for (int k = 0; k < 16; k += 2) {
        accu8(u[k], f[k], a0, a1);     ssA += f[k];
        accu8(u[k + 1], f[k + 1], c0, c1); ssB += f[k + 1];
      }
    }
    for (; j + 3 < e1; j += 4) {
      const int s0 = col[j], s1 = col[j + 1], s2 = col[j + 2], s3 = col[j + 3];
      const uint2 u0 = *(const uint2*)&hs8[(size_t)s0 * DD + c8];
      const uint2 u1 = *(const uint2*)&hs8[(size_t)s1 * DD + c8];
      const uint2 u2 = *(const uint2*)&hs8[(size_t)s2 * DD + c8];
      const uint2 u3 = *(const uint2*)&hs8[(size_t)s3 * DD + c8];
      const float f0 = scalev[s0], f1 = scalev[s1], f2 = scalev[s2], f3 = scalev[s3];
      accu8(u0, f0, a0, a1); ssA += f0;
      accu8(u1, f1, c0, c1); ssB += f1;
      accu8(u2, f2, a0, a1); ssA += f2;
      accu8(u3, f3, c0, c1); ssB += f3;
    }
    for (; j < e1; ++j) {
      const int s0 = col[j];
      const float f0 = scalev[s0];
      accu8(*(const uint2*)&hs8[(size_t)s0 * DD + c8], f0, a0, a1);
      ssA += f0;
    }
    a0.x += c0.x; a0.y += c0.y; a0.z += c0.z; a0.w += c0.w;
    a1.x += c1.x; a1.y += c1.y; a1.z += c1.z; a1.w += c1.w;
    const float corr = 128.0f * (ssA + ssB);
    a0.x -= corr; a0.y -= corr; a0.z -= corr; a0.w -= corr;
    a1.x -= corr; a1.y -= corr; a1.z -= corr; a1.w -= corr;
    const float dv = dinv[d];
    const float4 bb0 = *(const float4*)&bias[c8];
    const float4 bb1 = *(const float4*)&bias[c8 + 4];
    float4 o0, o1;
    o0.x = fmaxf(fmaf(a0.x, dv, bb0.x), 0.f);
    o0.y = fmaxf(fmaf(a0.y, dv, bb0.y), 0.f);
    o0.z = fmaxf(fmaf(a0.z, dv, bb0.z), 0.f);
    o0.w = fmaxf(fmaf(a0.w, dv, bb0.w), 0.f);
    o1.x = fmaxf(fmaf(a1.x, dv, bb1.x), 0.f);
    o1.y = fmaxf(fmaf(a1.y, dv, bb1.y), 0.f);
    o1.z = fmaxf(fmaf(a1.z, dv, bb1.z), 0.f);
    o1.w = fmaxf(fmaf(a1.w, dv, bb1.w), 0.f);
    if (mode == 0) {
      uint4 pk;
      pk.x = pack2(o0.x, o0.y); pk.y = pack2(o0.z, o0.w);
      pk.z = pack2(o1.x, o1.y); pk.w = pack2(o1.z, o1.w);
      *(uint4*)&hout[(size_t)d * DD + c8] = pk;       // bf16 h for next gemm
      bs0 = o0; bs1 = o1;
      q0.x = o0.x * o0.x; q0.y = o0.y * o0.y;
      q0.z = o0.z * o0.z; q0.w = o0.w * o0.w;
      q1.x = o1.x * o1.x; q1.y = o1.y * o1.y;
      q1.z = o1.z * o1.z; q1.w = o1.w * o1.w;
    } else {
      // full JK sum: ((x + BN1(h1)) + BN2(h2)) + h3
      float4 v0 = *(const float4*)&x[(size_t)d * DD + c8];
      float4 v1 = *(const float4*)&x[(size_t)d * DD + c8 + 4];
      const uint4 uh1 = *(const uint4*)&h1b[(size_t)d * DD + c8];
      const uint4 uh2 = *(const uint4*)&h2b[(size_t)d * DD + c8];
      {
        const float4 sc0 = *(const float4*)&ss[c8];
        const float4 sc1 = *(const float4*)&ss[c8 + 4];
        const float4 sh0 = *(const float4*)&ss[128 + c8];
        const float4 sh1 = *(const float4*)&ss[128 + c8 + 4];
        v0.x += fmaf(bflo(uh1.x), sc0.x, sh0.x);
        v0.y += fmaf(bfhi(uh1.x), sc0.y, sh0.y);
        v0.z += fmaf(bflo(uh1.y), sc0.z, sh0.z);
        v0.w += fmaf(bfhi(uh1.y), sc0.w, sh0.w);
        v1.x += fmaf(bflo(uh1.z), sc1.x, sh1.x);
        v1.y += fmaf(bfhi(uh1.z), sc1.y, sh1.y);
        v1.z += fmaf(bflo(uh1.w), sc1.z, sh1.z);
        v1.w += fmaf(bfhi(uh1.w), sc1.w, sh1.w);
      }
      {
        const float4 sc0 = *(const float4*)&ss[256 + c8];
        const float4 sc1 = *(const float4*)&ss[256 + c8 + 4];
        const float4 sh0 = *(const float4*)&ss[384 + c8];
        const float4 sh1 = *(const float4*)&ss[384 + c8 + 4];
        v0.x += fmaf(bflo(uh2.x), sc0.x, sh0.x);
        v0.y += fmaf(bfhi(uh2.x), sc0.y, sh0.y);
        v0.z += fmaf(bflo(uh2.y), sc0.z, sh0.z);
        v0.w += fmaf(bfhi(uh2.y), sc0.w, sh0.w);
        v1.x += fmaf(bflo(uh2.z), sc1.x, sh1.x);
        v1.y += fmaf(bfhi(uh2.z), sc1.y, sh1.y);
        v1.z += fmaf(bflo(uh2.w), sc1.z, sh1.z);
        v1.w += fmaf(bfhi(uh2.w), sc1.w, sh1.w);
      }
      v0.x += o0.x; v0.y += o0.y; v0.z += o0.z; v0.w += o0.w;
      v1.x += o1.x; v1.y += o1.y; v1.z += o1.z; v1.w += o1.w;
      *(float4*)&out[(size_t)d * DD + c8] = v0;
      *(float4*)&out[(size_t)d * DD + c8 + 4] = v1;
    }
  }
  if (mode == 0) {
    __shared__ float red[256 * 16];
    float* my = &red[threadIdx.x * 16];
    my[0] = bs0.x; my[1] = bs0.y; my[2] = bs0.z; my[3] = bs0.w;
    my[4] = bs1.x; my[5] = bs1.y; my[6] = bs1.z; my[7] = bs1.w;
    my[8] = q0.x;  my[9] = q0.y;  my[10] = q0.z; my[11] = q0.w;
    my[12] = q1.x; my[13] = q1.y; my[14] = q1.z; my[15] = q1.w;
    __syncthreads();
    const int t = threadIdx.x;
    float s = 0.f;
#pragma unroll
    for (int gg = 0; gg < 16; ++gg) s += red[gg * 256 + t];
    partials[(size_t)blockIdx.x * 256 + t] = s;   // coalesced
  }
}

// --- BN-stat reduction phase 1: coalesced ---
__global__ __launch_bounds__(256)
void k_bnred(const float* __restrict__ partials, float* __restrict__ stat2) {
  const int t = threadIdx.x;
  const int j = blockIdx.x;              // 0..249
  float v = 0.f;
#pragma unroll 5
  for (int r = 0; r < 25; ++r)
    v += partials[(size_t)(j * 25 + r) * 256 + t];
  stat2[(size_t)j * 256 + t] = v;
}

// --- BN-stat finish ---
__global__ __launch_bounds__(256)
void k_bnfin(const float* __restrict__ stat2, float* __restrict__ ss,
             const float* __restrict__ gamma, const float* __restrict__ beta) {
  __shared__ float tot[256];            // [kind*128 + c]
  const int t = threadIdx.x;
  float s = 0.f;
  for (int j = 0; j < BNRED_GRID; ++j)
    s += stat2[(size_t)j * 256 + t];
  const int lane16 = t >> 4, q = t & 15;
  const int c = lane16 * 8 + (q & 7), kind = q >> 3;
  tot[kind * 128 + c] = s;
  __syncthreads();
  if (t < 128) {
    const float m = tot[t] * (1.0f / NN);
    const float var = tot[128 + t] * (1.0f / NN) - m * m;
    const float rs = rsqrtf(var + BN_EPS);
    const float sc = rs * gamma[t];
    ss[t] = sc;
    ss[128 + t] = beta[t] - m * sc;
  }
}

extern "C" void kernel_launch(void* const* d_in, const int* in_sizes, int n_in,
                              void* d_out, int out_size, void* d_ws, size_t ws_size,
                              hipStream_t stream) {
  const float* x = (const float*)d_in[0];
  const int* ei = (const int*)d_in[1];
  const float* W = (const float*)d_in[2];
  const float* b = (const float*)d_in[3];
  const float* gamma = (const float*)d_in[4];
  const float* beta = (const float*)d_in[5];
  float* out = (float*)d_out;
  const int* srcv = ei;
  const int* dstv = ei + EE;

  char* w = (char*)d_ws;
  int* rowptr = (int*)w;     w += (size_t)NPAD * 4;
  float* dinv = (float*)w;   w += (size_t)NPAD * 4;
  float* scalev = (float*)w; w += (size_t)NPAD * 4;
  int* cntT = (int*)w;       w += (size_t)NBK * CSTRIDE * 4;
  int* baseT = (int*)w;      w += (size_t)NBK * CSTRIDE * 4;
  int* gtot = (int*)w;       w += 256 * 4;
  float* ss = (float*)w;     w += 512 * 4;        // [l][scale|shift] x2 layers
  float* stat2 = (float*)w;  w += (size_t)BNRED_GRID * 256 * 4;   // 256KB
  int* col = (int*)w;        w += (size_t)EE * 4;
  unsigned short* Wt = (unsigned short*)w; w += (size_t)3 * DD * DD * 2;
  // ebuf (CSR-build only) aliases partials (spmm/bnred only); both 6.4 MB
  unsigned* ebuf = (unsigned*)w;
  float* partials = (float*)w; w += (size_t)EE * 4;
  unsigned short* h1b = (unsigned short*)w; w += (size_t)NN * DD * 2;  // h1 (bf16)
  unsigned short* h2b = (unsigned short*)w; w += (size_t)NN * DD * 2;  // h2 (bf16)
  unsigned char* hs8 = (unsigned char*)w;                              // hs (u8)

  k_cnt<<<PART_GRID, 256, 0, stream>>>(dstv, cntT);
  k_colscan<<<NBK, 64, 0, stream>>>(cntT, baseT, gtot);
  k_part2<<<PART_GRID, 256, 0, stream>>>(srcv, dstv, baseT, gtot, ebuf);
  k_csr2<<<NBK, 256, 0, stream>>>(ebuf, gtot, rowptr, col, dinv);
  k_wt<<<3, 256, 0, stream>>>(W, Wt);

  // l=0: A = x (fp32), no BN
  k_gemm<<<GEMM_GRID, 256, 0, stream>>>(x, nullptr, Wt, dinv, hs8, scalev,
                                        nullptr);
  k_spmm<<<SPMM_GRID, 256, 0, stream>>>(hs8, scalev, rowptr, col, dinv, b,
                                        h1b, partials,
                                        nullptr, nullptr, nullptr, nullptr,
                                        nullptr, 0);
  k_bnred<<<BNRED_GRID, 256, 0, stream>>>(partials, stat2);
  k_bnfin<<<1, 256, 0, stream>>>(stat2, ss, gamma, beta);

  // l=1: A = BN1(h1) fused (bf16)
  k_gemm<<<GEMM_GRID, 256, 0, stream>>>(nullptr, h1b, Wt + (size_t)DD * DD,
                                        dinv, hs8, scalev, ss);
  k_spmm<<<SPMM_GRID, 256, 0, stream>>>(hs8, scalev, rowptr, col, dinv, b + DD,
                                        h2b, partials,
                                        nullptr, nullptr, nullptr, nullptr,
                                        nullptr, 0);
  k_bnred<<<BNRED_GRID, 256, 0, stream>>>(partials, stat2);
  k_bnfin<<<1, 256, 0, stream>>>(stat2, ss + 256, gamma + DD, beta + DD);

  // l=2: A = BN2(h2) fused (bf16); final spmm does the whole JK sum
  k_gemm<<<GEMM_GRID, 256, 0, stream>>>(nullptr, h2b, Wt + (size_t)2 * DD * DD,
                                        dinv, hs8, scalev, ss + 256);
  k_spmm<<<SPMM_GRID, 256, 0, stream>>>(hs8, scalev, rowptr, col, dinv,
                                        b + 2 * DD, nullptr, nullptr,
                                        x, h1b, h2b, ss, out, 1);
}

// Round 12
// 448.976 us; speedup vs baseline: 1.0911x; 1.0911x over previous
//
#include <hip/hip_runtime.h>
#include <hip/hip_bf16.h>

// GCN (3-layer, JK=sum) on MI355X.
// R16: R15 post-mortem — the 16-deep unroll REGRESSED (59.6->68.9us spmm,
//      occupancy 50->35%, VGPR 40->56): random-gather throughput is
//      TLP-bound; per-wave ILP doesn't substitute for resident waves.
//      R16 = R14's exact 8-edge loop (452us baseline) + ONLY the
//      biased-uint8 decode (v_cvt_f32_ubyteN, 2 VALU/ch vs 3; per-row
//      -128*sum(sc) correction, reassociation ~1e-6).
// R14: coalesced two-phase bnred; k_bktscan folded into part2/csr2.
// R13: hsb int8 + per-row scale (128B gather granule). R11: JK-sum deferred
//      to final spmm. R10: h bf16. R9: BN affine fused into gemm A-path.
// R8: LDS radix partition CSR build. R7: MFMA gemm.

constexpr int NN = 100000;
constexpr int EE = 1600000;
constexpr int DD = 128;
constexpr float BN_EPS = 1e-5f;
constexpr int NPAD = 100096;
constexpr int SPMM_GRID = NN / 16;              // 6250
constexpr int GEMM_GRID = (NN + 63) / 64;       // 1563
constexpr int BNRED_GRID = 250;                 // 6250/25 rows each

// radix partition params
constexpr int NBK = (NN + 511) / 512;           // 196 coarse buckets (dst>>9)
constexpr int PB = 4096;                        // edges per partition block
constexpr int PART_GRID = (EE + PB - 1) / PB;   // 391
constexpr int CSTRIDE = 400;                    // >= PART_GRID, count-table stride
constexpr int CAPL = 10240;                     // LDS colseg capacity

typedef __attribute__((ext_vector_type(8))) short bf16x8;
typedef __attribute__((ext_vector_type(4))) float f32x4;

__device__ __forceinline__ float bfhi(unsigned int u) {
  union { unsigned int i; float f; } v; v.i = u & 0xffff0000u; return v.f;
}
__device__ __forceinline__ float bflo(unsigned int u) {
  union { unsigned int i; float f; } v; v.i = u << 16; return v.f;
}
__device__ __forceinline__ unsigned short f2bf(float f) {
  union { float f; unsigned int i; } v;
  v.f = f;
  unsigned int r = v.i + 0x7FFFu + ((v.i >> 16) & 1u);   // RNE
  return (unsigned short)(r >> 16);
}
__device__ __forceinline__ unsigned pack2(float lo, float hi) {
  return (unsigned)f2bf(lo) | ((unsigned)f2bf(hi) << 16);
}
// biased-uint8 decode: 8 channels from one uint2 (v_cvt_f32_ubyteN pattern)
__device__ __forceinline__ void accu8(uint2 u, float sc, float4& a0, float4& a1) {
  a0.x = fmaf(sc, (float)(u.x & 0xffu), a0.x);
  a0.y = fmaf(sc, (float)((u.x >> 8) & 0xffu), a0.y);
  a0.z = fmaf(sc, (float)((u.x >> 16) & 0xffu), a0.z);
  a0.w = fmaf(sc, (float)(u.x >> 24), a0.w);
  a1.x = fmaf(sc, (float)(u.y & 0xffu), a1.x);
  a1.y = fmaf(sc, (float)((u.y >> 8) & 0xffu), a1.y);
  a1.z = fmaf(sc, (float)((u.y >> 16) & 0xffu), a1.z);
  a1.w = fmaf(sc, (float)(u.y >> 24), a1.w);
}
__device__ __forceinline__ int wave_incl_scan(int v, int lane) {
#pragma unroll
  for (int off = 1; off < 64; off <<= 1) {
    int x = __shfl_up(v, off, 64);
    if (lane >= off) v += x;
  }
  return v;
}

// --- CSR build pass 1: per-(block,bucket) counts, transposed [bkt][blk] ---
__global__ __launch_bounds__(256)
void k_cnt(const int* __restrict__ dst, int* __restrict__ cntT) {
  __shared__ int cnt[256];
  const int t = threadIdx.x;
  const int e0 = blockIdx.x * PB;
  const int nv = min(PB, EE - e0);
  cnt[t] = 0;
  __syncthreads();
  for (int i = t; i < nv; i += 256)
    atomicAdd(&cnt[dst[e0 + i] >> 9], 1);
  __syncthreads();
  if (t < NBK) cntT[t * CSTRIDE + blockIdx.x] = cnt[t];
}

// --- per-bucket column scan over blocks; gtot[bkt] = total edges of bkt ---
__global__ __launch_bounds__(64)
void k_colscan(const int* __restrict__ cntT, int* __restrict__ baseT,
               int* __restrict__ gtot) {
  const int b = blockIdx.x;
  const int lane = threadIdx.x;
  int c[7];
  int ls = 0;
#pragma unroll
  for (int j = 0; j < 7; ++j) {
    const int idx = lane * 7 + j;
    c[j] = (idx < PART_GRID) ? cntT[b * CSTRIDE + idx] : 0;
    ls += c[j];
  }
  const int is = wave_incl_scan(ls, lane);
  int run = is - ls;
#pragma unroll
  for (int j = 0; j < 7; ++j) {
    const int idx = lane * 7 + j;
    if (idx < PART_GRID) baseT[b * CSTRIDE + idx] = run;
    run += c[j];
  }
  if (lane == 63) gtot[b] = is;
}

// --- CSR build pass 2: LDS counting sort per block, coalesced ebuf writes ---
__global__ __launch_bounds__(256)
void k_part2(const int* __restrict__ src, const int* __restrict__ dst,
             const int* __restrict__ baseT, const int* __restrict__ gtot,
             unsigned* __restrict__ ebuf) {
  __shared__ unsigned sorted[PB];
  __shared__ unsigned char sortedb[PB];
  alignas(16) __shared__ int cnt[256];
  __shared__ int cur[256], start[256], gbase[256];
  __shared__ int bktb[200];
  const int t = threadIdx.x;
  const int lane = t & 63;
  const int e0 = blockIdx.x * PB;
  const int nv = min(PB, EE - e0);
  cnt[t] = 0;
  if (t < 64) {   // recompute exclusive bucket-base scan from gtot
    int c[4];
    int ls = 0;
#pragma unroll
    for (int j = 0; j < 4; ++j) {
      const int idx = t * 4 + j;
      c[j] = (idx < NBK) ? gtot[idx] : 0;
      ls += c[j];
    }
    const int is = wave_incl_scan(ls, t);
    int run = is - ls;
#pragma unroll
    for (int j = 0; j < 4; ++j) {
      const int idx = t * 4 + j;
      if (idx < NBK) bktb[idx] = run;
      run += c[j];
    }
  }
  __syncthreads();
  if (t < NBK) gbase[t] = bktb[t] + baseT[t * CSTRIDE + blockIdx.x];
  int es[PB / 256], ed[PB / 256];
#pragma unroll
  for (int j = 0; j < PB / 256; ++j) {
    const int i = t + j * 256;
    if (i < nv) {
      es[j] = src[e0 + i];
      ed[j] = dst[e0 + i];
      atomicAdd(&cnt[ed[j] >> 9], 1);
    } else {
      ed[j] = -1;
    }
  }
  __syncthreads();
  if (t < 64) {
    const int4 c = *(const int4*)&cnt[lane * 4];
    const int ls = c.x + c.y + c.z + c.w;
    const int is = wave_incl_scan(ls, lane);
    int run = is - ls;
    start[lane * 4] = run; cur[lane * 4] = run; run += c.x;
    start[lane * 4 + 1] = run; cur[lane * 4 + 1] = run; run += c.y;
    start[lane * 4 + 2] = run; cur[lane * 4 + 2] = run; run += c.z;
    start[lane * 4 + 3] = run; cur[lane * 4 + 3] = run;
  }
  __syncthreads();
#pragma unroll
  for (int j = 0; j < PB / 256; ++j) {
    if (ed[j] >= 0) {
      const int bkt = ed[j] >> 9;
      const int p = atomicAdd(&cur[bkt], 1);
      sorted[p] = ((unsigned)es[j] << 9) | (unsigned)(ed[j] & 511);
      sortedb[p] = (unsigned char)bkt;
    }
  }
  __syncthreads();
  for (int i = t; i < nv; i += 256) {
    const int bkt = sortedb[i];
    ebuf[(size_t)gbase[bkt] + (i - start[bkt])] = sorted[i];
  }
}

// --- CSR finish: one block per bucket, all writes coalesced ---
__global__ __launch_bounds__(256)
void k_csr2(const unsigned* __restrict__ ebuf, const int* __restrict__ gtot,
            int* __restrict__ rowptr, int* __restrict__ col,
            float* __restrict__ dinv) {
  __shared__ int rowcnt[512], rowbase[512], rowcur[512];
  __shared__ int bktb[200];
  __shared__ unsigned colseg[CAPL];
  const int b = blockIdx.x;
  const int t = threadIdx.x;
  if (t < 64) {   // recompute exclusive bucket-base scan (+ total at [NBK])
    int c[4];
    int ls = 0;
#pragma unroll
    for (int j = 0; j < 4; ++j) {
      const int idx = t * 4 + j;
      c[j] = (idx < NBK) ? gtot[idx] : 0;
      ls += c[j];
    }
    const int is = wave_incl_scan(ls, t);
    int run = is - ls;
#pragma unroll
    for (int j = 0; j < 4; ++j) {
      const int idx = t * 4 + j;
      if (idx < NBK) bktb[idx] = run;
      run += c[j];
    }
    if (t == 63) bktb[NBK] = is;
  }
  rowcnt[t] = 0;
  rowcnt[t + 256] = 0;
  __syncthreads();
  const int ebase = bktb[b];
  const int n = min(bktb[b + 1] - ebase, CAPL);
  const unsigned* eb = &ebuf[ebase];
  for (int i = t; i < n; i += 256)
    atomicAdd(&rowcnt[eb[i] & 511u], 1);
  __syncthreads();
  if (t < 64) {
    int v[8];
    int ls = 0;
#pragma unroll
    for (int j = 0; j < 8; ++j) { v[j] = rowcnt[t * 8 + j]; ls += v[j]; }
    const int is = wave_incl_scan(ls, t);
    int run = is - ls;
#pragma unroll
    for (int j = 0; j < 8; ++j) {
      rowbase[t * 8 + j] = run;
      rowcur[t * 8 + j] = run;
      run += v[j];
    }
  }
  __syncthreads();
#pragma unroll
  for (int h = 0; h < 2; ++h) {
    const int rl = t + h * 256;
    const int r = b * 512 + rl;
    if (r < NN) {
      rowptr[r] = ebase + rowbase[rl];
      dinv[r] = rsqrtf((float)rowcnt[rl] + 1.0f);
    }
  }
  if (b == NBK - 1 && t == 0) rowptr[NN] = ebase + n;
  for (int i = t; i < n; i += 256) {
    const unsigned u = eb[i];
    const int p = atomicAdd(&rowcur[u & 511u], 1);
    colseg[p] = u >> 9;
  }
  __syncthreads();
  for (int i = t; i < n; i += 256) col[ebase + i] = (int)colseg[i];
}

// --- W transpose+cvt: Wt[l][c][k] = bf16(W[l][k][c]) --- grid = 3 blocks
__global__ __launch_bounds__(256)
void k_wt(const float* __restrict__ W, unsigned short* __restrict__ Wt) {
  const float* Ws = W + (size_t)blockIdx.x * DD * DD;
  unsigned short* Wo = Wt + (size_t)blockIdx.x * DD * DD;
  for (int i = threadIdx.x; i < DD * DD; i += 256) {
    const int k = i >> 7, c = i & 127;
    Wo[c * DD + k] = f2bf(Ws[i]);
  }
}

// --- MFMA GEMM with optional fused BN affine on A; biased-uint8 output ---
__global__ __launch_bounds__(256)
void k_gemm(const float* __restrict__ hf, const unsigned short* __restrict__ hb,
            const unsigned short* __restrict__ Wt,
            const float* __restrict__ dinv, unsigned char* __restrict__ hs8,
            float* __restrict__ scalev, const float* __restrict__ ss) {
  const int lane = threadIdx.x & 63;
  const int wave = threadIdx.x >> 6;          // 0..3
  const int n15 = lane & 15;
  const int quad = lane >> 4;                 // 0..3
  const int rbase = blockIdx.x * 64 + wave * 16;
  const int r0 = rbase + n15;
  const int arow = (r0 < NN) ? r0 : NN - 1;   // clamped load row

  f32x4 acc[8];
#pragma unroll
  for (int ct = 0; ct < 8; ++ct) acc[ct] = (f32x4){0.f, 0.f, 0.f, 0.f};

#pragma unroll
  for (int kc = 0; kc < 4; ++kc) {
    const int k0 = kc * 32 + quad * 8;
    float4 a0, a1;
    if (hb) {   // bf16 h (one 16B load covers all 8 elems)
      const uint4 u = *(const uint4*)&hb[(size_t)arow * DD + k0];
      a0.x = bflo(u.x); a0.y = bfhi(u.x);
      a0.z = bflo(u.y); a0.w = bfhi(u.y);
      a1.x = bflo(u.z); a1.y = bfhi(u.z);
      a1.z = bflo(u.w); a1.w = bfhi(u.w);
    } else {
      a0 = *(const float4*)&hf[(size_t)arow * DD + k0];
      a1 = *(const float4*)&hf[(size_t)arow * DD + k0 + 4];
    }
    if (ss) {  // fused BatchNorm affine
      const float4 sc0 = *(const float4*)&ss[k0];
      const float4 sc1 = *(const float4*)&ss[k0 + 4];
      const float4 sh0 = *(const float4*)&ss[128 + k0];
      const float4 sh1 = *(const float4*)&ss[128 + k0 + 4];
      a0.x = fmaf(a0.x, sc0.x, sh0.x); a0.y = fmaf(a0.y, sc0.y, sh0.y);
      a0.z = fmaf(a0.z, sc0.z, sh0.z); a0.w = fmaf(a0.w, sc0.w, sh0.w);
      a1.x = fmaf(a1.x, sc1.x, sh1.x); a1.y = fmaf(a1.y, sc1.y, sh1.y);
      a1.z = fmaf(a1.z, sc1.z, sh1.z); a1.w = fmaf(a1.w, sc1.w, sh1.w);
    }
    bf16x8 af;
    af[0] = (short)f2bf(a0.x); af[1] = (short)f2bf(a0.y);
    af[2] = (short)f2bf(a0.z); af[3] = (short)f2bf(a0.w);
    af[4] = (short)f2bf(a1.x); af[5] = (short)f2bf(a1.y);
    af[6] = (short)f2bf(a1.z); af[7] = (short)f2bf(a1.w);
#pragma unroll
    for (int ct = 0; ct < 8; ++ct) {
      const bf16x8 bf = *(const bf16x8*)&Wt[(size_t)(ct * 16 + n15) * DD + k0];
      acc[ct] = __builtin_amdgcn_mfma_f32_16x16x32_bf16(af, bf, acc[ct], 0, 0, 0);
    }
  }

#pragma unroll
  for (int i = 0; i < 4; ++i) {
    const int r = rbase + quad * 4 + i;
    const int rr = (r < NN) ? r : NN - 1;
    const float dv = dinv[rr];
    float v[8];
    float m = 0.f;
#pragma unroll
    for (int ct = 0; ct < 8; ++ct) {
      v[ct] = acc[ct][i] * dv;
      m = fmaxf(m, fabsf(v[ct]));
    }
    // row max across the 16-lane column group (all lanes execute)
#pragma unroll
    for (int off = 1; off < 16; off <<= 1)
      m = fmaxf(m, __shfl_xor(m, off, 64));
    const float inv = (m > 0.f) ? 127.0f / m : 0.f;
    if (r < NN) {
#pragma unroll
      for (int ct = 0; ct < 8; ++ct) {
        const int q = __float2int_rn(v[ct] * inv) + 128;   // biased uint8
        hs8[(size_t)r * DD + ct * 16 + n15] = (unsigned char)(q & 0xff);
      }
      if (n15 == 0) scalev[r] = m * (1.0f / 127.0f);
    }
  }
}

// --- SpMM over biased-uint8 hsb + row scales: R14's 8-edge dual-acc loop.
//     channel value = sum(sc*u) - 128*sum(sc).
//     mode 0: hout = bf16(relu(...)), partials for BN stats.
//     mode 1: out = ((x + BN1(h1)) + BN2(h2)) + relu(...)  (full JK sum) ---
__global__ __launch_bounds__(256)
void k_spmm(const unsigned char* __restrict__ hs8,
            const float* __restrict__ scalev, const int* __restrict__ rowptr,
            const int* __restrict__ col, const float* __restrict__ dinv,
            const float* __restrict__ bias, unsigned short* __restrict__ hout,
            float* __restrict__ partials, const float* __restrict__ x,
            const unsigned short* __restrict__ h1b,
            const unsigned short* __restrict__ h2b,
            const float* __restrict__ ss, float* __restrict__ out,
            const int mode) {
  const int lane = threadIdx.x & 15;     // 16 lanes / row
  const int g = threadIdx.x >> 4;        // 0..15 rows / block
  const int c8 = lane * 8;               // channel (and byte) offset
  const int d = blockIdx.x * 16 + g;
  float4 a0 = make_float4(0.f, 0.f, 0.f, 0.f);
  float4 a1 = make_float4(0.f, 0.f, 0.f, 0.f);
  float4 c0 = a0, c1 = a0;               // second accumulator pair
  float ssA = 0.f, ssB = 0.f;            // scale sums (bias correction)
  float4 bs0 = a0, bs1 = a0, q0 = a0, q1 = a0;
  if (d < NN) {
    {
      const float sc = scalev[d];        // self-loop
      accu8(*(const uint2*)&hs8[(size_t)d * DD + c8], sc, a0, a1);
      ssA += sc;
    }
    int j = rowptr[d];
    const int e1 = rowptr[d + 1];
    for (; j + 7 < e1; j += 8) {
      const int s0 = col[j],     s1 = col[j + 1], s2 = col[j + 2], s3 = col[j + 3];
      const int s4 = col[j + 4], s5 = col[j + 5], s6 = col[j + 6], s7 = col[j + 7];
      const uint2 u0 = *(const uint2*)&hs8[(size_t)s0 * DD + c8];
      const uint2 u1 = *(const uint2*)&hs8[(size_t)s1 * DD + c8];
      const uint2 u2 = *(const uint2*)&hs8[(size_t)s2 * DD + c8];
      const uint2 u3 = *(const uint2*)&hs8[(size_t)s3 * DD + c8];
      const uint2 u4 = *(const uint2*)&hs8[(size_t)s4 * DD + c8];
      const uint2 u5 = *(const uint2*)&hs8[(size_t)s5 * DD + c8];
      const uint2 u6 = *(const uint2*)&hs8[(size_t)s6 * DD + c8];
      const uint2 u7 = *(const uint2*)&hs8[(size_t)s7 * DD + c8];
      const float f0 = scalev[s0], f1 = scalev[s1], f2 = scalev[s2], f3 = scalev[s3];
      const float f4 = scalev[s4], f5 = scalev[s5], f6 = scalev[s6], f7 = scalev[s7];
      accu8(u0, f0, a0, a1); ssA += f0;
      accu8(u1, f1, c0, c1); ssB += f1;
      accu8(u2, f2, a0, a1); ssA += f2;
      accu8(u3, f3, c0, c1); ssB += f3;
      accu8(u4, f4, a0, a1); ssA += f4;
      accu8(u5, f5, c0, c1); ssB += f5;
      accu8(u6, f6, a0, a1); ssA += f6;
      accu8(u7, f7, c0, c1); ssB += f7;
    }
    for (; j + 3 < e1; j += 4) {
      const int s0 = col[j], s1 = col[j + 1], s2 = col[j + 2], s3 = col[j + 3];
      const uint2 u0 = *(const uint2*)&hs8[(size_t)s0 * DD + c8];
      const uint2 u1 = *(const uint2*)&hs8[(size_t)s1 * DD + c8];
      const uint2 u2 = *(const uint2*)&hs8[(size_t)s2 * DD + c8];
      const uint2 u3 = *(const uint2*)&hs8[(size_t)s3 * DD + c8];
      const float f0 = scalev[s0], f1 = scalev[s1], f2 = scalev[s2], f3 = scalev[s3];
      accu8(u0, f0, a0, a1); ssA += f0;
      accu8(u1, f1, c0, c1); ssB += f1;
      accu8(u2, f2, a0, a1); ssA += f2;
      accu8(u3, f3, c0, c1); ssB += f3;
    }
    for (; j < e1; ++j) {
      const int s0 = col[j];
      const float f0 = scalev[s0];
      accu8(*(const uint2*)&hs8[(size_t)s0 * DD + c8], f0, a0, a1);
      ssA += f0;
    }
    a0.x += c0.x; a0.y += c0.y; a0.z += c0.z; a0.w += c0.w;
    a1.x += c1.x; a1.y += c1.y; a1.z += c1.z; a1.w += c1.w;
    const float corr = 128.0f * (ssA + ssB);
    a0.x -= corr; a0.y -= corr; a0.z -= corr; a0.w -= corr;
    a1.x -= corr; a1.y -= corr; a1.z -= corr; a1.w -= corr;
    const float dv = dinv[d];
    const float4 bb0 = *(const float4*)&bias[c8];
    const float4 bb1 = *(const float4*)&bias[c8 + 4];
    float4 o0, o1;
    o0.x = fmaxf(fmaf(a0.x, dv, bb0.x), 0.f);
    o0.y = fmaxf(fmaf(a0.y, dv, bb0.y), 0.f);
    o0.z = fmaxf(fmaf(a0.z, dv, bb0.z), 0.f);
    o0.w = fmaxf(fmaf(a0.w, dv, bb0.w), 0.f);
    o1.x = fmaxf(fmaf(a1.x, dv, bb1.x), 0.f);
    o1.y = fmaxf(fmaf(a1.y, dv, bb1.y), 0.f);
    o1.z = fmaxf(fmaf(a1.z, dv, bb1.z), 0.f);
    o1.w = fmaxf(fmaf(a1.w, dv, bb1.w), 0.f);
    if (mode == 0) {
      uint4 pk;
      pk.x = pack2(o0.x, o0.y); pk.y = pack2(o0.z, o0.w);
      pk.z = pack2(o1.x, o1.y); pk.w = pack2(o1.z, o1.w);
      *(uint4*)&hout[(size_t)d * DD + c8] = pk;       // bf16 h for next gemm
      bs0 = o0; bs1 = o1;
      q0.x = o0.x * o0.x; q0.y = o0.y * o0.y;
      q0.z = o0.z * o0.z; q0.w = o0.w * o0.w;
      q1.x = o1.x * o1.x; q1.y = o1.y * o1.y;
      q1.z = o1.z * o1.z; q1.w = o1.w * o1.w;
    } else {
      // full JK sum: ((x + BN1(h1)) + BN2(h2)) + h3
      float4 v0 = *(const float4*)&x[(size_t)d * DD + c8];
      float4 v1 = *(const float4*)&x[(size_t)d * DD + c8 + 4];
      const uint4 uh1 = *(const uint4*)&h1b[(size_t)d * DD + c8];
      const uint4 uh2 = *(const uint4*)&h2b[(size_t)d * DD + c8];
      {
        const float4 sc0 = *(const float4*)&ss[c8];
        const float4 sc1 = *(const float4*)&ss[c8 + 4];
        const float4 sh0 = *(const float4*)&ss[128 + c8];
        const float4 sh1 = *(const float4*)&ss[128 + c8 + 4];
        v0.x += fmaf(bflo(uh1.x), sc0.x, sh0.x);
        v0.y += fmaf(bfhi(uh1.x), sc0.y, sh0.y);
        v0.z += fmaf(bflo(uh1.y), sc0.z, sh0.z);
        v0.w += fmaf(bfhi(uh1.y), sc0.w, sh0.w);
        v1.x += fmaf(bflo(uh1.z), sc1.x, sh1.x);
        v1.y += fmaf(bfhi(uh1.z), sc1.y, sh1.y);
        v1.z += fmaf(bflo(uh1.w), sc1.z, sh1.z);
        v1.w += fmaf(bfhi(uh1.w), sc1.w, sh1.w);
      }
      {
        const float4 sc0 = *(const float4*)&ss[256 + c8];
        const float4 sc1 = *(const float4*)&ss[256 + c8 + 4];
        const float4 sh0 = *(const float4*)&ss[384 + c8];
        const float4 sh1 = *(const float4*)&ss[384 + c8 + 4];
        v0.x += fmaf(bflo(uh2.x), sc0.x, sh0.x);
        v0.y += fmaf(bfhi(uh2.x), sc0.y, sh0.y);
        v0.z += fmaf(bflo(uh2.y), sc0.z, sh0.z);
        v0.w += fmaf(bfhi(uh2.y), sc0.w, sh0.w);
        v1.x += fmaf(bflo(uh2.z), sc1.x, sh1.x);
        v1.y += fmaf(bfhi(uh2.z), sc1.y, sh1.y);
        v1.z += fmaf(bflo(uh2.w), sc1.z, sh1.z);
        v1.w += fmaf(bfhi(uh2.w), sc1.w, sh1.w);
      }
      v0.x += o0.x; v0.y += o0.y; v0.z += o0.z; v0.w += o0.w;
      v1.x += o1.x; v1.y += o1.y; v1.z += o1.z; v1.w += o1.w;
      *(float4*)&out[(size_t)d * DD + c8] = v0;
      *(float4*)&out[(size_t)d * DD + c8 + 4] = v1;
    }
  }
  if (mode == 0) {
    __shared__ float red[256 * 16];
    float* my = &red[threadIdx.x * 16];
    my[0] = bs0.x; my[1] = bs0.y; my[2] = bs0.z; my[3] = bs0.w;
    my[4] = bs1.x; my[5] = bs1.y; my[6] = bs1.z; my[7] = bs1.w;
    my[8] = q0.x;  my[9] = q0.y;  my[10] = q0.z; my[11] = q0.w;
    my[12] = q1.x; my[13] = q1.y; my[14] = q1.z; my[15] = q1.w;
    __syncthreads();
    const int t = threadIdx.x;
    float s = 0.f;
#pragma unroll
    for (int gg = 0; gg < 16; ++gg) s += red[gg * 256 + t];
    partials[(size_t)blockIdx.x * 256 + t] = s;   // coalesced
  }
}

// --- BN-stat reduction phase 1: coalesced ---
__global__ __launch_bounds__(256)
void k_bnred(const float* __restrict__ partials, float* __restrict__ stat2) {
  const int t = threadIdx.x;
  const int j = blockIdx.x;              // 0..249
  float v = 0.f;
#pragma unroll 5
  for (int r = 0; r < 25; ++r)
    v += partials[(size_t)(j * 25 + r) * 256 + t];
  stat2[(size_t)j * 256 + t] = v;
}

// --- BN-stat finish ---
__global__ __launch_bounds__(256)
void k_bnfin(const float* __restrict__ stat2, float* __restrict__ ss,
             const float* __restrict__ gamma, const float* __restrict__ beta) {
  __shared__ float tot[256];            // [kind*128 + c]
  const int t = threadIdx.x;
  float s = 0.f;
  for (int j = 0; j < BNRED_GRID; ++j)
    s += stat2[(size_t)j * 256 + t];
  const int lane16 = t >> 4, q = t & 15;
  const int c = lane16 * 8 + (q & 7), kind = q >> 3;
  tot[kind * 128 + c] = s;
  __syncthreads();
  if (t < 128) {
    const float m = tot[t] * (1.0f / NN);
    const float var = tot[128 + t] * (1.0f / NN) - m * m;
    const float rs = rsqrtf(var + BN_EPS);
    const float sc = rs * gamma[t];
    ss[t] = sc;
    ss[128 + t] = beta[t] - m * sc;
  }
}

extern "C" void kernel_launch(void* const* d_in, const int* in_sizes, int n_in,
                              void* d_out, int out_size, void* d_ws, size_t ws_size,
                              hipStream_t stream) {
  const float* x = (const float*)d_in[0];
  const int* ei = (const int*)d_in[1];
  const float* W = (const float*)d_in[2];
  const float* b = (const float*)d_in[3];
  const float* gamma = (const float*)d_in[4];
  const float* beta = (const float*)d_in[5];
  float* out = (float*)d_out;
  const int* srcv = ei;
  const int* dstv = ei + EE;

  char* w = (char*)d_ws;
  int* rowptr = (int*)w;     w += (size_t)NPAD * 4;
  float* dinv = (float*)w;   w += (size_t)NPAD * 4;
  float* scalev = (float*)w; w += (size_t)NPAD * 4;
  int* cntT = (int*)w;       w += (size_t)NBK * CSTRIDE * 4;
  int* baseT = (int*)w;      w += (size_t)NBK * CSTRIDE * 4;
  int* gtot = (int*)w;       w += 256 * 4;
  float* ss = (float*)w;     w += 512 * 4;        // [l][scale|shift] x2 layers
  float* stat2 = (float*)w;  w += (size_t)BNRED_GRID * 256 * 4;   // 256KB
  int* col = (int*)w;        w += (size_t)EE * 4;
  unsigned short* Wt = (unsigned short*)w; w += (size_t)3 * DD * DD * 2;
  // ebuf (CSR-build only) aliases partials (spmm/bnred only); both 6.4 MB
  unsigned* ebuf = (unsigned*)w;
  float* partials = (float*)w; w += (size_t)EE * 4;
  unsigned short* h1b = (unsigned short*)w; w += (size_t)NN * DD * 2;  // h1 (bf16)
  unsigned short* h2b = (unsigned short*)w; w += (size_t)NN * DD * 2;  // h2 (bf16)
  unsigned char* hs8 = (unsigned char*)w;                              // hs (u8)

  k_cnt<<<PART_GRID, 256, 0, stream>>>(dstv, cntT);
  k_colscan<<<NBK, 64, 0, stream>>>(cntT, baseT, gtot);
  k_part2<<<PART_GRID, 256, 0, stream>>>(srcv, dstv, baseT, gtot, ebuf);
  k_csr2<<<NBK, 256, 0, stream>>>(ebuf, gtot, rowptr, col, dinv);
  k_wt<<<3, 256, 0, stream>>>(W, Wt);

  // l=0: A = x (fp32), no BN
  k_gemm<<<GEMM_GRID, 256, 0, stream>>>(x, nullptr, Wt, dinv, hs8, scalev,
                                        nullptr);
  k_spmm<<<SPMM_GRID, 256, 0, stream>>>(hs8, scalev, rowptr, col, dinv, b,
                                        h1b, partials,
                                        nullptr, nullptr, nullptr, nullptr,
                                        nullptr, 0);
  k_bnred<<<BNRED_GRID, 256, 0, stream>>>(partials, stat2);
  k_bnfin<<<1, 256, 0, stream>>>(stat2, ss, gamma, beta);

  // l=1: A = BN1(h1) fused (bf16)
  k_gemm<<<GEMM_GRID, 256, 0, stream>>>(nullptr, h1b, Wt + (size_t)DD * DD,
                                        dinv, hs8, scalev, ss);
  k_spmm<<<SPMM_GRID, 256, 0, stream>>>(hs8, scalev, rowptr, col, dinv, b + DD,
                                        h2b, partials,
                                        nullptr, nullptr, nullptr, nullptr,
                                        nullptr, 0);
  k_bnred<<<BNRED_GRID, 256, 0, stream>>>(partials, stat2);
  k_bnfin<<<1, 256, 0, stream>>>(stat2, ss + 256, gamma + DD, beta + DD);

  // l=2: A = BN2(h2) fused (bf16); final spmm does the whole JK sum
  k_gemm<<<GEMM_GRID, 256, 0, stream>>>(nullptr, h2b, Wt + (size_t)2 * DD * DD,
                                        dinv, hs8, scalev, ss + 256);
  k_spmm<<<SPMM_GRID, 256, 0, stream>>>(hs8, scalev, rowptr, col, dinv,
                                        b + 2 * DD, nullptr, nullptr,
                                        x, h1b, h2b, ss, out, 1);
}